// Round 4
// baseline (551.125 us; speedup 1.0000x reference)
//
#include <hip/hip_runtime.h>

// ---------------------------------------------------------------------------
// T5GNNAdapt: LN -> RGCN scatter-mean (2 relations) -> [h0|h1|x] @ [W0;W1;root]
//             + bias -> relu -> @wo -> + residual
// Shapes: B=8,S=1024,D=1024,F=4096,E=262144,N=B*S=8192, K_cat=3072
// R3->R4: aggregate_kernel restructured for gather MLP: 4 edge-groups (1 wave
// each, 32B/lane), unroll-2 over edges -> 4 loads in flight (was ~1), LDS
// cross-group reduce. GEMM unchanged (at m97 structural plateau, 936 TF).
// ---------------------------------------------------------------------------

typedef unsigned short u16;
typedef unsigned int   u32;
typedef __attribute__((ext_vector_type(8))) short bf16x8;
typedef __attribute__((ext_vector_type(4))) float f32x4;

#define E_NUM  262144
#define NNODE  8192
#define NBKT   (2 * NNODE)      // 16384 (rel,dst) buckets
#define DDIM   1024
#define FDIM   4096
#define KCAT   3072
#define LN_EPS 1e-6f

struct alignas(8) u16x4 { u16 x, y, z, w; };

__device__ __forceinline__ u16 f2bf(float f) {
  u32 u = __float_as_uint(f);
  u32 r = u + 0x7fffu + ((u >> 16) & 1u);   // RNE
  return (u16)(r >> 16);
}
__device__ __forceinline__ float bf2f(u16 h) {
  return __uint_as_float(((u32)h) << 16);
}

// 16-byte global -> LDS async copy (wave-uniform LDS base + lane*16 layout)
#define GLD16(gp, lp)                                              \
  __builtin_amdgcn_global_load_lds(                                \
      (__attribute__((address_space(1))) u32*)(gp),                \
      (__attribute__((address_space(3))) u32*)(lp), 16, 0, 0)

// ---------------------------------------------------------------------------
// K1: LayerNorm (one-pass sum/sumsq). One block per row; writes bf16 x into
// hcat[:, 2048:3072].
// ---------------------------------------------------------------------------
__global__ void ln_kernel(const float* __restrict__ hs,
                          const float* __restrict__ gamma,
                          const float* __restrict__ beta,
                          u16* __restrict__ hcat) {
  const int row = blockIdx.x;
  const int tid = threadIdx.x;
  const float4 v = ((const float4*)(hs + (size_t)row * DDIM))[tid];

  __shared__ float r1[256], r2[256];
  r1[tid] = v.x + v.y + v.z + v.w;
  r2[tid] = v.x * v.x + v.y * v.y + v.z * v.z + v.w * v.w;
  __syncthreads();
  for (int st = 128; st > 0; st >>= 1) {
    if (tid < st) { r1[tid] += r1[tid + st]; r2[tid] += r2[tid + st]; }
    __syncthreads();
  }
  const float mean = r1[0] * (1.0f / DDIM);
  const float var  = r2[0] * (1.0f / DDIM) - mean * mean;
  const float rs   = rsqrtf(var + LN_EPS);

  const int base = tid * 4;
  const float4 g = *(const float4*)(gamma + base);
  const float4 b = *(const float4*)(beta + base);
  u16x4 o;
  o.x = f2bf((v.x - mean) * rs * g.x + b.x);
  o.y = f2bf((v.y - mean) * rs * g.y + b.y);
  o.z = f2bf((v.z - mean) * rs * g.z + b.z);
  o.w = f2bf((v.w - mean) * rs * g.w + b.w);
  *(u16x4*)(hcat + (size_t)row * KCAT + 2048 + base) = o;
}

// ---------------------------------------------------------------------------
// K2: f32 [K,N] -> bf16 [N,K] transpose (stitches two sources along K).
// ---------------------------------------------------------------------------
__global__ void cvt_transpose(const float* __restrict__ srcA,
                              const float* __restrict__ srcB,
                              int splitK, int K, int N,
                              u16* __restrict__ dst) {
  __shared__ float tile[32][33];
  const int n0 = blockIdx.x * 32, k0 = blockIdx.y * 32;
  const int tx = threadIdx.x, ty = threadIdx.y;
  for (int i = ty; i < 32; i += 8) {
    const int k = k0 + i;
    const float v = (k < splitK) ? srcA[(size_t)k * N + n0 + tx]
                                 : srcB[(size_t)(k - splitK) * N + n0 + tx];
    tile[i][tx] = v;
  }
  __syncthreads();
  for (int i = ty; i < 32; i += 8) {
    dst[(size_t)(n0 + i) * K + k0 + tx] = f2bf(tile[tx][i]);
  }
}

// ---------------------------------------------------------------------------
// K3a: count edges per (rel,dst) bucket.
// ---------------------------------------------------------------------------
__global__ void count_kernel(const int* __restrict__ edge_index,
                             const int* __restrict__ edge_type,
                             int* __restrict__ cnt) {
  const int e = blockIdx.x * 256 + threadIdx.x;
  const int d = edge_index[E_NUM + e];
  const int r = edge_type[e];
  atomicAdd(&cnt[r * NNODE + d], 1);
}

// ---------------------------------------------------------------------------
// K3b: exclusive prefix sum over 16384 counts (single block, 1024 thr).
// ---------------------------------------------------------------------------
__global__ __launch_bounds__(1024) void scan_kernel(const int* __restrict__ cnt,
                                                    int* __restrict__ off,
                                                    int* __restrict__ cursor) {
  __shared__ int partial[1024];
  const int tid  = threadIdx.x;
  const int base = tid * 16;
  int local[16];
  int s = 0;
#pragma unroll
  for (int i = 0; i < 16; ++i) { local[i] = s; s += cnt[base + i]; }
  partial[tid] = s;
  __syncthreads();
  for (int st = 1; st < 1024; st <<= 1) {
    const int v = (tid >= st) ? partial[tid - st] : 0;
    __syncthreads();
    partial[tid] += v;
    __syncthreads();
  }
  const int pre = (tid == 0) ? 0 : partial[tid - 1];
#pragma unroll
  for (int i = 0; i < 16; ++i) {
    const int o = pre + local[i];
    off[base + i]    = o;
    cursor[base + i] = o;
  }
}

// ---------------------------------------------------------------------------
// K3c: scatter edge SOURCE ids into buckets (4B per edge, not 4KB rows).
// ---------------------------------------------------------------------------
__global__ void fill_kernel(const int* __restrict__ edge_index,
                            const int* __restrict__ edge_type,
                            int* __restrict__ cursor,
                            int* __restrict__ bucket_src) {
  const int e = blockIdx.x * 256 + threadIdx.x;
  const int s = edge_index[e];
  const int d = edge_index[E_NUM + e];
  const int r = edge_type[e];
  const int pos = atomicAdd(&cursor[r * NNODE + d], 1);
  bucket_src[pos] = s;
}

// ---------------------------------------------------------------------------
// K4: per-(rel,node) aggregation. 4 edge-groups x 64 lanes; each lane covers
// 16 cols (32B = 2 adjacent uint4 loads) so one wave reads a full 2KB row per
// edge, coalesced. Edge loop unrolled x2 -> 4 independent loads in flight per
// thread. Cross-group reduce via LDS. No atomics.
// ---------------------------------------------------------------------------
__device__ __forceinline__ void acc8(float* a, const uint4 q) {
  a[0] += bf2f((u16)(q.x & 0xffffu)); a[1] += bf2f((u16)(q.x >> 16));
  a[2] += bf2f((u16)(q.y & 0xffffu)); a[3] += bf2f((u16)(q.y >> 16));
  a[4] += bf2f((u16)(q.z & 0xffffu)); a[5] += bf2f((u16)(q.z >> 16));
  a[6] += bf2f((u16)(q.w & 0xffffu)); a[7] += bf2f((u16)(q.w >> 16));
}

__global__ __launch_bounds__(256) void aggregate_kernel(
    const int* __restrict__ cnt, const int* __restrict__ off,
    const int* __restrict__ bucket_src, u16* __restrict__ hcat) {
  const int b    = blockIdx.x;            // r*NNODE + node
  const int r    = b >> 13;
  const int node = b & (NNODE - 1);
  const int tid  = threadIdx.x;
  const int g    = tid >> 6;              // edge-group 0..3 (one wave each)
  const int c    = tid & 63;              // col chunk: cols c*16 .. c*16+15
  const int n     = cnt[b];
  const int start = off[b];

  __shared__ int   ids[256];
  __shared__ float red[3 * 1024];
  float a[16] = {};

  for (int c0 = 0; c0 < n; c0 += 256) {
    const int m = min(n - c0, 256);
    __syncthreads();
    if (tid < m) ids[tid] = bucket_src[start + c0 + tid];
    __syncthreads();
    int j = g;
    for (; j + 4 < m; j += 8) {           // unroll 2: edges j and j+4
      const int s0 = ids[j], s1 = ids[j + 4];
      const u16* p0 = hcat + (size_t)s0 * KCAT + 2048 + c * 16;
      const u16* p1 = hcat + (size_t)s1 * KCAT + 2048 + c * 16;
      const uint4 x0 = *(const uint4*)(p0);
      const uint4 x1 = *(const uint4*)(p0 + 8);
      const uint4 y0 = *(const uint4*)(p1);
      const uint4 y1 = *(const uint4*)(p1 + 8);
      acc8(a + 0, x0); acc8(a + 8, x1);
      acc8(a + 0, y0); acc8(a + 8, y1);
    }
    for (; j < m; j += 4) {               // remainder
      const int s0 = ids[j];
      const u16* p0 = hcat + (size_t)s0 * KCAT + 2048 + c * 16;
      const uint4 x0 = *(const uint4*)(p0);
      const uint4 x1 = *(const uint4*)(p0 + 8);
      acc8(a + 0, x0); acc8(a + 8, x1);
    }
  }

  // cross-group reduce: groups 1..3 dump partials, group 0 sums + stores.
  if (g != 0) {
    float* d = red + (g - 1) * 1024 + c * 16;
#pragma unroll
    for (int i = 0; i < 4; ++i)
      *(float4*)(d + i * 4) = make_float4(a[i*4+0], a[i*4+1], a[i*4+2], a[i*4+3]);
  }
  __syncthreads();
  if (g == 0) {
#pragma unroll
    for (int k = 0; k < 3; ++k) {
      const float* d = red + k * 1024 + c * 16;
#pragma unroll
      for (int i = 0; i < 16; ++i) a[i] += d[i];
    }
    const float inv = 1.0f / fmaxf((float)n, 1.0f);
    uint4 o0, o1;
    o0.x = (u32)f2bf(a[0] * inv)  | ((u32)f2bf(a[1] * inv)  << 16);
    o0.y = (u32)f2bf(a[2] * inv)  | ((u32)f2bf(a[3] * inv)  << 16);
    o0.z = (u32)f2bf(a[4] * inv)  | ((u32)f2bf(a[5] * inv)  << 16);
    o0.w = (u32)f2bf(a[6] * inv)  | ((u32)f2bf(a[7] * inv)  << 16);
    o1.x = (u32)f2bf(a[8] * inv)  | ((u32)f2bf(a[9] * inv)  << 16);
    o1.y = (u32)f2bf(a[10] * inv) | ((u32)f2bf(a[11] * inv) << 16);
    o1.z = (u32)f2bf(a[12] * inv) | ((u32)f2bf(a[13] * inv) << 16);
    o1.w = (u32)f2bf(a[14] * inv) | ((u32)f2bf(a[15] * inv) << 16);
    u16* dp = hcat + (size_t)node * KCAT + (size_t)r * DDIM + c * 16;
    *(uint4*)(dp)     = o0;
    *(uint4*)(dp + 8) = o1;
  }
}

// ---------------------------------------------------------------------------
// GEMM: C[M,N] = A[M,K] @ Bt[N,K]^T   (both bf16, fp32 accum)
// 128x128 tile, BK=64, XOR-swizzled LDS (R3: conflicts 2.5e7 -> 0, 936 TF).
// EPI=0: out = bf16(relu(C + bias[col]))        -> obf
// EPI=1: out = f32(C + resid)                   -> of32
// ---------------------------------------------------------------------------
template <int EPI>
__global__ __launch_bounds__(256) void gemm_bt(
    const u16* __restrict__ A, const u16* __restrict__ Bt,
    int M, int N, int K,
    const float* __restrict__ bias, const float* __restrict__ resid,
    u16* __restrict__ obf, float* __restrict__ of32) {
  __shared__ __align__(16) u16 sA[128 * 64];
  __shared__ __align__(16) u16 sB[128 * 64];
  const int tid  = threadIdx.x;
  const int lane = tid & 63;
  const int wave = tid >> 6;
  const int bm = blockIdx.x * 128;
  const int bn = blockIdx.y * 128;
  const int wm = (wave >> 1) * 64;
  const int wn = (wave & 1) * 64;
  const int lr   = lane & 15;
  const int quad = lane >> 4;

  f32x4 acc[4][4] = {};

  const u16* gA[4]; const u16* gB[4]; u16* lA[4]; u16* lB[4];
#pragma unroll
  for (int i = 0; i < 4; ++i) {
    const int s   = tid + 256 * i;
    const int row = s >> 3;
    const int seg = (s & 7) ^ (row & 7);
    gA[i] = A  + (size_t)(bm + row) * K + seg * 8;
    gB[i] = Bt + (size_t)(bn + row) * K + seg * 8;
    lA[i] = sA + s * 8;
    lB[i] = sB + s * 8;
  }

  int ai[4][2], bi[4][2];
#pragma unroll
  for (int mi = 0; mi < 4; ++mi) {
#pragma unroll
    for (int h = 0; h < 2; ++h) {
      const int ra = wm + mi * 16 + lr;
      ai[mi][h] = ra * 8 + ((h * 4 + quad) ^ (ra & 7));
      const int rb = wn + mi * 16 + lr;
      bi[mi][h] = rb * 8 + ((h * 4 + quad) ^ (rb & 7));
    }
  }

  for (int k0 = 0; k0 < K; k0 += 64) {
#pragma unroll
    for (int i = 0; i < 4; ++i) {
      GLD16(gA[i] + k0, lA[i]);
      GLD16(gB[i] + k0, lB[i]);
    }
    __syncthreads();

    const bf16x8* pA = (const bf16x8*)sA;
    const bf16x8* pB = (const bf16x8*)sB;
#pragma unroll
    for (int h = 0; h < 2; ++h) {
      bf16x8 av[4], bv[4];
#pragma unroll
      for (int mi = 0; mi < 4; ++mi) av[mi] = pA[ai[mi][h]];
#pragma unroll
      for (int ni = 0; ni < 4; ++ni) bv[ni] = pB[bi[ni][h]];
#pragma unroll
      for (int mi = 0; mi < 4; ++mi)
#pragma unroll
        for (int ni = 0; ni < 4; ++ni)
          acc[mi][ni] = __builtin_amdgcn_mfma_f32_16x16x32_bf16(
              av[mi], bv[ni], acc[mi][ni], 0, 0, 0);
    }
    __syncthreads();
  }

#pragma unroll
  for (int mi = 0; mi < 4; ++mi) {
#pragma unroll
    for (int ni = 0; ni < 4; ++ni) {
      const int col  = bn + wn + ni * 16 + lr;
      const int row0 = bm + wm + mi * 16 + quad * 4;
      if constexpr (EPI == 0) {
        const float bb = bias[col];
#pragma unroll
        for (int r = 0; r < 4; ++r) {
          float v = acc[mi][ni][r] + bb;
          v = fmaxf(v, 0.0f);
          obf[(size_t)(row0 + r) * N + col] = f2bf(v);
        }
      } else {
#pragma unroll
        for (int r = 0; r < 4; ++r) {
          const size_t idx = (size_t)(row0 + r) * N + col;
          of32[idx] = resid[idx] + acc[mi][ni][r];
        }
      }
    }
  }
}

// ---------------------------------------------------------------------------
// Workspace layout (bytes):
//   hcat       [8192 x 3072] bf16              @ 0          (50331648)
//   WcatT      [4096 x 3072] bf16              @ 50331648   (25165824)
//   woT        [1024 x 4096] bf16              @ 75497472   ( 8388608)
//   out1       [8192 x 4096] bf16              @ 83886080   (67108864)
//     bucket_src [262144] i32 (aliases out1)   @ 83886080   ( 1048576)
//     cnt        [16384] i32                   @ 84934656   (   65536)
//     off        [16384] i32                   @ 85000192   (   65536)
//     cursor     [16384] i32                   @ 85065728   (   65536)
// total: 150994944 bytes (144 MB)
// ---------------------------------------------------------------------------
extern "C" void kernel_launch(void* const* d_in, const int* in_sizes, int n_in,
                              void* d_out, int out_size, void* d_ws, size_t ws_size,
                              hipStream_t stream) {
  const float* hs     = (const float*)d_in[0];
  const float* weight = (const float*)d_in[1];   // [2,1024,4096]
  const float* root   = (const float*)d_in[2];   // [1024,4096]
  const float* bias   = (const float*)d_in[3];   // [4096]
  const float* wo     = (const float*)d_in[4];   // [4096,1024]
  const float* gamma  = (const float*)d_in[5];
  const float* beta   = (const float*)d_in[6];
  const int* edge_index = (const int*)d_in[7];   // [2,E]
  const int* edge_type  = (const int*)d_in[8];   // [E]
  float* out = (float*)d_out;

  char* ws = (char*)d_ws;
  u16*   hcat       = (u16*)(ws + 0);
  u16*   WcatT      = (u16*)(ws + 50331648);
  u16*   woT        = (u16*)(ws + 75497472);
  u16*   out1       = (u16*)(ws + 83886080);
  int*   bucket_src = (int*)(ws + 83886080);     // aliases out1 (consumed pre-GEMM1)
  int*   cnt        = (int*)(ws + 84934656);
  int*   off        = (int*)(ws + 85000192);
  int*   cursor     = (int*)(ws + 85065728);

  (void)hipMemsetAsync(cnt, 0, 65536, stream);

  ln_kernel<<<NNODE, 256, 0, stream>>>(hs, gamma, beta, hcat);

  cvt_transpose<<<dim3(FDIM / 32, KCAT / 32), dim3(32, 8), 0, stream>>>(
      weight, root, 2048, KCAT, FDIM, WcatT);
  cvt_transpose<<<dim3(DDIM / 32, FDIM / 32), dim3(32, 8), 0, stream>>>(
      wo, wo, FDIM, FDIM, DDIM, woT);

  count_kernel<<<E_NUM / 256, 256, 0, stream>>>(edge_index, edge_type, cnt);
  scan_kernel<<<1, 1024, 0, stream>>>(cnt, off, cursor);
  fill_kernel<<<E_NUM / 256, 256, 0, stream>>>(edge_index, edge_type, cursor, bucket_src);
  aggregate_kernel<<<NBKT, 256, 0, stream>>>(cnt, off, bucket_src, hcat);

  // out1 = relu([h0|h1|x] @ [W0;W1;root] + bias)   [8192 x 4096] bf16
  gemm_bt<0><<<dim3(8192 / 128, FDIM / 128), 256, 0, stream>>>(
      hcat, WcatT, 8192, FDIM, KCAT, bias, nullptr, out1, nullptr);

  // out = hs + out1 @ wo                            [8192 x 1024] f32
  gemm_bt<1><<<dim3(8192 / 128, DDIM / 128), 256, 0, stream>>>(
      out1, woT, 8192, DDIM, FDIM, nullptr, hs, nullptr, out);
}

// Round 5
// 525.617 us; speedup vs baseline: 1.0485x; 1.0485x over previous
//
#include <hip/hip_runtime.h>

// ---------------------------------------------------------------------------
// T5GNNAdapt: LN -> RGCN scatter-mean (2 relations) -> [h0|h1|x] @ [W0;W1;root]
//             + bias -> relu -> @wo -> + residual
// Shapes: B=8,S=1024,D=1024,F=4096,E=262144,N=B*S=8192, K_cat=3072
// R4->R5: aggregation gather switched to fp8 e4m3 from dense xq[8192x1024]
// (8MB): halves gather bytes (512->256MB) AND halves the L2-miss fraction
// (footprint 16->8MB vs 4MB/XCD L2). GEMMs/x-direct-path stay bf16.
// R4 lesson: aggregate is gather-BW-bound (~2.6TB/s wall), not latency-bound.
// ---------------------------------------------------------------------------

typedef unsigned short u16;
typedef unsigned int   u32;
typedef __attribute__((ext_vector_type(8))) short bf16x8;
typedef __attribute__((ext_vector_type(4))) float f32x4;
typedef __attribute__((ext_vector_type(2))) float f32x2;

#define E_NUM  262144
#define NNODE  8192
#define NBKT   (2 * NNODE)      // 16384 (rel,dst) buckets
#define DDIM   1024
#define FDIM   4096
#define KCAT   3072
#define LN_EPS 1e-6f

struct alignas(8) u16x4 { u16 x, y, z, w; };

__device__ __forceinline__ u16 f2bf(float f) {
  u32 u = __float_as_uint(f);
  u32 r = u + 0x7fffu + ((u >> 16) & 1u);   // RNE
  return (u16)(r >> 16);
}
__device__ __forceinline__ float bf2f(u16 h) {
  return __uint_as_float(((u32)h) << 16);
}

// ---- fp8 e4m3fn (OCP) encode/decode; HW cvt when available ---------------
__device__ __forceinline__ u32 enc_fp8_1(float f) {
  u32 u = __float_as_uint(f);
  u32 s = u >> 31;
  u32 mag = u & 0x7fffffffu;
  mag = mag + 0x7ffffu + ((mag >> 20) & 1u);          // RNE to 3 mant bits
  if (mag > 0x43e00000u) mag = 0x43e00000u;           // clamp to 448
  u32 e = mag >> 23;
  return (e <= 120u) ? 0u                              // flush denorm/zero
                     : ((s << 7) | ((e - 120u) << 3) | ((mag >> 20) & 7u));
}

__device__ __forceinline__ u32 pack4_fp8(float a, float b, float c, float d) {
#if __has_builtin(__builtin_amdgcn_cvt_pk_fp8_f32)
  int v = 0;
  v = __builtin_amdgcn_cvt_pk_fp8_f32(a, b, v, false);  // bytes 0,1
  v = __builtin_amdgcn_cvt_pk_fp8_f32(c, d, v, true);   // bytes 2,3
  return (u32)v;
#else
  return enc_fp8_1(a) | (enc_fp8_1(b) << 8) | (enc_fp8_1(c) << 16) |
         (enc_fp8_1(d) << 24);
#endif
}

__device__ __forceinline__ float dec_fp8_1(u32 b) {
  u32 e = (b >> 3) & 15u;
  u32 f = ((b & 0x80u) << 24) | ((e + 120u) << 23) | ((b & 7u) << 20);
  return e ? __uint_as_float(f) : 0.0f;
}

__device__ __forceinline__ void acc4_fp8(float* a, u32 q) {
#if __has_builtin(__builtin_amdgcn_cvt_pk_f32_fp8)
  f32x2 p0 = __builtin_amdgcn_cvt_pk_f32_fp8((int)q, false);
  f32x2 p1 = __builtin_amdgcn_cvt_pk_f32_fp8((int)q, true);
  a[0] += p0.x; a[1] += p0.y; a[2] += p1.x; a[3] += p1.y;
#else
  a[0] += dec_fp8_1(q);       a[1] += dec_fp8_1(q >> 8);
  a[2] += dec_fp8_1(q >> 16); a[3] += dec_fp8_1(q >> 24);
#endif
}

// 16-byte global -> LDS async copy (wave-uniform LDS base + lane*16 layout)
#define GLD16(gp, lp)                                              \
  __builtin_amdgcn_global_load_lds(                                \
      (__attribute__((address_space(1))) u32*)(gp),                \
      (__attribute__((address_space(3))) u32*)(lp), 16, 0, 0)

// ---------------------------------------------------------------------------
// K1: LayerNorm (one-pass). Writes bf16 x into hcat[:, 2048:3072] AND fp8
// copy into dense xq[8192x1024] (aggregation gather input).
// ---------------------------------------------------------------------------
__global__ void ln_kernel(const float* __restrict__ hs,
                          const float* __restrict__ gamma,
                          const float* __restrict__ beta,
                          u16* __restrict__ hcat,
                          u32* __restrict__ xq) {
  const int row = blockIdx.x;
  const int tid = threadIdx.x;
  const float4 v = ((const float4*)(hs + (size_t)row * DDIM))[tid];

  __shared__ float r1[256], r2[256];
  r1[tid] = v.x + v.y + v.z + v.w;
  r2[tid] = v.x * v.x + v.y * v.y + v.z * v.z + v.w * v.w;
  __syncthreads();
  for (int st = 128; st > 0; st >>= 1) {
    if (tid < st) { r1[tid] += r1[tid + st]; r2[tid] += r2[tid + st]; }
    __syncthreads();
  }
  const float mean = r1[0] * (1.0f / DDIM);
  const float var  = r2[0] * (1.0f / DDIM) - mean * mean;
  const float rs   = rsqrtf(var + LN_EPS);

  const int base = tid * 4;
  const float4 g = *(const float4*)(gamma + base);
  const float4 b = *(const float4*)(beta + base);
  const float o0 = (v.x - mean) * rs * g.x + b.x;
  const float o1 = (v.y - mean) * rs * g.y + b.y;
  const float o2 = (v.z - mean) * rs * g.z + b.z;
  const float o3 = (v.w - mean) * rs * g.w + b.w;
  u16x4 o;
  o.x = f2bf(o0); o.y = f2bf(o1); o.z = f2bf(o2); o.w = f2bf(o3);
  *(u16x4*)(hcat + (size_t)row * KCAT + 2048 + base) = o;
  xq[row * 256 + tid] = pack4_fp8(o0, o1, o2, o3);
}

// ---------------------------------------------------------------------------
// K2: f32 [K,N] -> bf16 [N,K] transpose (stitches two sources along K).
// ---------------------------------------------------------------------------
__global__ void cvt_transpose(const float* __restrict__ srcA,
                              const float* __restrict__ srcB,
                              int splitK, int K, int N,
                              u16* __restrict__ dst) {
  __shared__ float tile[32][33];
  const int n0 = blockIdx.x * 32, k0 = blockIdx.y * 32;
  const int tx = threadIdx.x, ty = threadIdx.y;
  for (int i = ty; i < 32; i += 8) {
    const int k = k0 + i;
    const float v = (k < splitK) ? srcA[(size_t)k * N + n0 + tx]
                                 : srcB[(size_t)(k - splitK) * N + n0 + tx];
    tile[i][tx] = v;
  }
  __syncthreads();
  for (int i = ty; i < 32; i += 8) {
    dst[(size_t)(n0 + i) * K + k0 + tx] = f2bf(tile[tx][i]);
  }
}

// ---------------------------------------------------------------------------
// K3a: count edges per (rel,dst) bucket.
// ---------------------------------------------------------------------------
__global__ void count_kernel(const int* __restrict__ edge_index,
                             const int* __restrict__ edge_type,
                             int* __restrict__ cnt) {
  const int e = blockIdx.x * 256 + threadIdx.x;
  const int d = edge_index[E_NUM + e];
  const int r = edge_type[e];
  atomicAdd(&cnt[r * NNODE + d], 1);
}

// ---------------------------------------------------------------------------
// K3b: exclusive prefix sum over 16384 counts (single block, 1024 thr).
// ---------------------------------------------------------------------------
__global__ __launch_bounds__(1024) void scan_kernel(const int* __restrict__ cnt,
                                                    int* __restrict__ off,
                                                    int* __restrict__ cursor) {
  __shared__ int partial[1024];
  const int tid  = threadIdx.x;
  const int base = tid * 16;
  int local[16];
  int s = 0;
#pragma unroll
  for (int i = 0; i < 16; ++i) { local[i] = s; s += cnt[base + i]; }
  partial[tid] = s;
  __syncthreads();
  for (int st = 1; st < 1024; st <<= 1) {
    const int v = (tid >= st) ? partial[tid - st] : 0;
    __syncthreads();
    partial[tid] += v;
    __syncthreads();
  }
  const int pre = (tid == 0) ? 0 : partial[tid - 1];
#pragma unroll
  for (int i = 0; i < 16; ++i) {
    const int o = pre + local[i];
    off[base + i]    = o;
    cursor[base + i] = o;
  }
}

// ---------------------------------------------------------------------------
// K3c: scatter edge SOURCE ids into buckets (4B per edge, not row data).
// ---------------------------------------------------------------------------
__global__ void fill_kernel(const int* __restrict__ edge_index,
                            const int* __restrict__ edge_type,
                            int* __restrict__ cursor,
                            int* __restrict__ bucket_src) {
  const int e = blockIdx.x * 256 + threadIdx.x;
  const int s = edge_index[e];
  const int d = edge_index[E_NUM + e];
  const int r = edge_type[e];
  const int pos = atomicAdd(&cursor[r * NNODE + d], 1);
  bucket_src[pos] = s;
}

// ---------------------------------------------------------------------------
// K4: per-(rel,node) aggregation, fp8 gather. 4 edge-groups x 64 lanes; each
// lane covers 16 cols = 16B = one dwordx4 per edge (wave reads full 1KB fp8
// row). Cross-group reduce via LDS; f32 accumulate; bf16 mean into hcat.
// ---------------------------------------------------------------------------
__global__ __launch_bounds__(256) void aggregate_kernel(
    const int* __restrict__ cnt, const int* __restrict__ off,
    const int* __restrict__ bucket_src, const u32* __restrict__ xq,
    u16* __restrict__ hcat) {
  const int b    = blockIdx.x;            // r*NNODE + node
  const int r    = b >> 13;
  const int node = b & (NNODE - 1);
  const int tid  = threadIdx.x;
  const int g    = tid >> 6;              // edge-group 0..3 (one wave each)
  const int c    = tid & 63;              // col chunk: cols c*16 .. c*16+15
  const int n     = cnt[b];
  const int start = off[b];

  __shared__ int   ids[256];
  __shared__ float red[3 * 1024];
  float a[16] = {};

  for (int c0 = 0; c0 < n; c0 += 256) {
    const int m = min(n - c0, 256);
    __syncthreads();
    if (tid < m) ids[tid] = bucket_src[start + c0 + tid];
    __syncthreads();
    int j = g;
    for (; j + 4 < m; j += 8) {           // unroll 2 (group stride 4)
      const int s0 = ids[j], s1 = ids[j + 4];
      const uint4 x0 = *(const uint4*)(xq + s0 * 256 + c * 4);
      const uint4 x1 = *(const uint4*)(xq + s1 * 256 + c * 4);
      acc4_fp8(a + 0,  x0.x); acc4_fp8(a + 4,  x0.y);
      acc4_fp8(a + 8,  x0.z); acc4_fp8(a + 12, x0.w);
      acc4_fp8(a + 0,  x1.x); acc4_fp8(a + 4,  x1.y);
      acc4_fp8(a + 8,  x1.z); acc4_fp8(a + 12, x1.w);
    }
    for (; j < m; j += 4) {               // remainder
      const int s0 = ids[j];
      const uint4 x0 = *(const uint4*)(xq + s0 * 256 + c * 4);
      acc4_fp8(a + 0,  x0.x); acc4_fp8(a + 4,  x0.y);
      acc4_fp8(a + 8,  x0.z); acc4_fp8(a + 12, x0.w);
    }
  }

  // cross-group reduce: groups 1..3 dump partials, group 0 sums + stores.
  if (g != 0) {
    float* d = red + (g - 1) * 1024 + c * 16;
#pragma unroll
    for (int i = 0; i < 4; ++i)
      *(float4*)(d + i * 4) = make_float4(a[i*4+0], a[i*4+1], a[i*4+2], a[i*4+3]);
  }
  __syncthreads();
  if (g == 0) {
#pragma unroll
    for (int k = 0; k < 3; ++k) {
      const float* d = red + k * 1024 + c * 16;
#pragma unroll
      for (int i = 0; i < 16; ++i) a[i] += d[i];
    }
    const float inv = 1.0f / fmaxf((float)n, 1.0f);
    uint4 o0, o1;
    o0.x = (u32)f2bf(a[0] * inv)  | ((u32)f2bf(a[1] * inv)  << 16);
    o0.y = (u32)f2bf(a[2] * inv)  | ((u32)f2bf(a[3] * inv)  << 16);
    o0.z = (u32)f2bf(a[4] * inv)  | ((u32)f2bf(a[5] * inv)  << 16);
    o0.w = (u32)f2bf(a[6] * inv)  | ((u32)f2bf(a[7] * inv)  << 16);
    o1.x = (u32)f2bf(a[8] * inv)  | ((u32)f2bf(a[9] * inv)  << 16);
    o1.y = (u32)f2bf(a[10] * inv) | ((u32)f2bf(a[11] * inv) << 16);
    o1.z = (u32)f2bf(a[12] * inv) | ((u32)f2bf(a[13] * inv) << 16);
    o1.w = (u32)f2bf(a[14] * inv) | ((u32)f2bf(a[15] * inv) << 16);
    u16* dp = hcat + (size_t)node * KCAT + (size_t)r * DDIM + c * 16;
    *(uint4*)(dp)     = o0;
    *(uint4*)(dp + 8) = o1;
  }
}

// ---------------------------------------------------------------------------
// GEMM: C[M,N] = A[M,K] @ Bt[N,K]^T   (both bf16, fp32 accum)
// 128x128 tile, BK=64, XOR-swizzled LDS (R3: conflicts 2.5e7 -> 0, 936 TF —
// at the m97-structure source-level plateau).
// EPI=0: out = bf16(relu(C + bias[col]))        -> obf
// EPI=1: out = f32(C + resid)                   -> of32
// ---------------------------------------------------------------------------
template <int EPI>
__global__ __launch_bounds__(256) void gemm_bt(
    const u16* __restrict__ A, const u16* __restrict__ Bt,
    int M, int N, int K,
    const float* __restrict__ bias, const float* __restrict__ resid,
    u16* __restrict__ obf, float* __restrict__ of32) {
  __shared__ __align__(16) u16 sA[128 * 64];
  __shared__ __align__(16) u16 sB[128 * 64];
  const int tid  = threadIdx.x;
  const int lane = tid & 63;
  const int wave = tid >> 6;
  const int bm = blockIdx.x * 128;
  const int bn = blockIdx.y * 128;
  const int wm = (wave >> 1) * 64;
  const int wn = (wave & 1) * 64;
  const int lr   = lane & 15;
  const int quad = lane >> 4;

  f32x4 acc[4][4] = {};

  const u16* gA[4]; const u16* gB[4]; u16* lA[4]; u16* lB[4];
#pragma unroll
  for (int i = 0; i < 4; ++i) {
    const int s   = tid + 256 * i;
    const int row = s >> 3;
    const int seg = (s & 7) ^ (row & 7);
    gA[i] = A  + (size_t)(bm + row) * K + seg * 8;
    gB[i] = Bt + (size_t)(bn + row) * K + seg * 8;
    lA[i] = sA + s * 8;
    lB[i] = sB + s * 8;
  }

  int ai[4][2], bi[4][2];
#pragma unroll
  for (int mi = 0; mi < 4; ++mi) {
#pragma unroll
    for (int h = 0; h < 2; ++h) {
      const int ra = wm + mi * 16 + lr;
      ai[mi][h] = ra * 8 + ((h * 4 + quad) ^ (ra & 7));
      const int rb = wn + mi * 16 + lr;
      bi[mi][h] = rb * 8 + ((h * 4 + quad) ^ (rb & 7));
    }
  }

  for (int k0 = 0; k0 < K; k0 += 64) {
#pragma unroll
    for (int i = 0; i < 4; ++i) {
      GLD16(gA[i] + k0, lA[i]);
      GLD16(gB[i] + k0, lB[i]);
    }
    __syncthreads();

    const bf16x8* pA = (const bf16x8*)sA;
    const bf16x8* pB = (const bf16x8*)sB;
#pragma unroll
    for (int h = 0; h < 2; ++h) {
      bf16x8 av[4], bv[4];
#pragma unroll
      for (int mi = 0; mi < 4; ++mi) av[mi] = pA[ai[mi][h]];
#pragma unroll
      for (int ni = 0; ni < 4; ++ni) bv[ni] = pB[bi[ni][h]];
#pragma unroll
      for (int mi = 0; mi < 4; ++mi)
#pragma unroll
        for (int ni = 0; ni < 4; ++ni)
          acc[mi][ni] = __builtin_amdgcn_mfma_f32_16x16x32_bf16(
              av[mi], bv[ni], acc[mi][ni], 0, 0, 0);
    }
    __syncthreads();
  }

#pragma unroll
  for (int mi = 0; mi < 4; ++mi) {
#pragma unroll
    for (int ni = 0; ni < 4; ++ni) {
      const int col  = bn + wn + ni * 16 + lr;
      const int row0 = bm + wm + mi * 16 + quad * 4;
      if constexpr (EPI == 0) {
        const float bb = bias[col];
#pragma unroll
        for (int r = 0; r < 4; ++r) {
          float v = acc[mi][ni][r] + bb;
          v = fmaxf(v, 0.0f);
          obf[(size_t)(row0 + r) * N + col] = f2bf(v);
        }
      } else {
#pragma unroll
        for (int r = 0; r < 4; ++r) {
          const size_t idx = (size_t)(row0 + r) * N + col;
          of32[idx] = resid[idx] + acc[mi][ni][r];
        }
      }
    }
  }
}

// ---------------------------------------------------------------------------
// Workspace layout (bytes):
//   hcat       [8192 x 3072] bf16              @ 0          (50331648)
//   WcatT      [4096 x 3072] bf16              @ 50331648   (25165824)
//   woT        [1024 x 4096] bf16              @ 75497472   ( 8388608)
//   out1       [8192 x 4096] bf16              @ 83886080   (67108864)
//     bucket_src [262144] i32 (aliases out1)   @ 83886080   ( 1048576)
//     cnt        [16384] i32                   @ 84934656   (   65536)
//     off        [16384] i32                   @ 85000192   (   65536)
//     cursor     [16384] i32                   @ 85065728   (   65536)
//     xq         [8192 x 1024] fp8             @ 85131264   ( 8388608)
//   (all aliased scratch consumed before GEMM1 writes out1)
// total: 150994944 bytes (144 MB)
// ---------------------------------------------------------------------------
extern "C" void kernel_launch(void* const* d_in, const int* in_sizes, int n_in,
                              void* d_out, int out_size, void* d_ws, size_t ws_size,
                              hipStream_t stream) {
  const float* hs     = (const float*)d_in[0];
  const float* weight = (const float*)d_in[1];   // [2,1024,4096]
  const float* root   = (const float*)d_in[2];   // [1024,4096]
  const float* bias   = (const float*)d_in[3];   // [4096]
  const float* wo     = (const float*)d_in[4];   // [4096,1024]
  const float* gamma  = (const float*)d_in[5];
  const float* beta   = (const float*)d_in[6];
  const int* edge_index = (const int*)d_in[7];   // [2,E]
  const int* edge_type  = (const int*)d_in[8];   // [E]
  float* out = (float*)d_out;

  char* ws = (char*)d_ws;
  u16*   hcat       = (u16*)(ws + 0);
  u16*   WcatT      = (u16*)(ws + 50331648);
  u16*   woT        = (u16*)(ws + 75497472);
  u16*   out1       = (u16*)(ws + 83886080);
  int*   bucket_src = (int*)(ws + 83886080);     // aliases out1 (consumed pre-GEMM1)
  int*   cnt        = (int*)(ws + 84934656);
  int*   off        = (int*)(ws + 85000192);
  int*   cursor     = (int*)(ws + 85065728);
  u32*   xq         = (u32*)(ws + 85131264);     // fp8 x, dense [8192][1024]

  (void)hipMemsetAsync(cnt, 0, 65536, stream);

  ln_kernel<<<NNODE, 256, 0, stream>>>(hs, gamma, beta, hcat, xq);

  cvt_transpose<<<dim3(FDIM / 32, KCAT / 32), dim3(32, 8), 0, stream>>>(
      weight, root, 2048, KCAT, FDIM, WcatT);
  cvt_transpose<<<dim3(DDIM / 32, FDIM / 32), dim3(32, 8), 0, stream>>>(
      wo, wo, FDIM, FDIM, DDIM, woT);

  count_kernel<<<E_NUM / 256, 256, 0, stream>>>(edge_index, edge_type, cnt);
  scan_kernel<<<1, 1024, 0, stream>>>(cnt, off, cursor);
  fill_kernel<<<E_NUM / 256, 256, 0, stream>>>(edge_index, edge_type, cursor, bucket_src);
  aggregate_kernel<<<NBKT, 256, 0, stream>>>(cnt, off, bucket_src, xq, hcat);

  // out1 = relu([h0|h1|x] @ [W0;W1;root] + bias)   [8192 x 4096] bf16
  gemm_bt<0><<<dim3(8192 / 128, FDIM / 128), 256, 0, stream>>>(
      hcat, WcatT, 8192, FDIM, KCAT, bias, nullptr, out1, nullptr);

  // out = hs + out1 @ wo                            [8192 x 1024] f32
  gemm_bt<1><<<dim3(8192 / 128, DDIM / 128), 256, 0, stream>>>(
      out1, woT, 8192, DDIM, FDIM, nullptr, hs, nullptr, out);
}

// Round 6
// 515.585 us; speedup vs baseline: 1.0689x; 1.0195x over previous
//
#include <hip/hip_runtime.h>

// ---------------------------------------------------------------------------
// T5GNNAdapt: LN -> RGCN scatter-mean (2 relations) -> [h0|h1|x] @ [W0;W1;root]
//             + bias -> relu -> @wo -> + residual
// Shapes: B=8,S=1024,D=1024,F=4096,E=262144,N=B*S=8192, K_cat=3072
// R5->R6: gemm2 retiled 128x128 -> 64x128 (512 -> 1024 blocks, 2 -> 4
// blocks/CU): at 2 blocks/CU the barrier vmcnt(0) drain was exposed every
// K-iter (occupancy-bound, ~200us for 68.7 GF). gemm1 unchanged (936 TF,
// m97-structure plateau). Kernels renamed for per-kernel profiling.
// ---------------------------------------------------------------------------

typedef unsigned short u16;
typedef unsigned int   u32;
typedef __attribute__((ext_vector_type(8))) short bf16x8;
typedef __attribute__((ext_vector_type(4))) float f32x4;
typedef __attribute__((ext_vector_type(2))) float f32x2;

#define E_NUM  262144
#define NNODE  8192
#define NBKT   (2 * NNODE)      // 16384 (rel,dst) buckets
#define DDIM   1024
#define FDIM   4096
#define KCAT   3072
#define LN_EPS 1e-6f

struct alignas(8) u16x4 { u16 x, y, z, w; };

__device__ __forceinline__ u16 f2bf(float f) {
  u32 u = __float_as_uint(f);
  u32 r = u + 0x7fffu + ((u >> 16) & 1u);   // RNE
  return (u16)(r >> 16);
}
__device__ __forceinline__ float bf2f(u16 h) {
  return __uint_as_float(((u32)h) << 16);
}

// ---- fp8 e4m3fn (OCP) encode/decode; HW cvt when available ---------------
__device__ __forceinline__ u32 enc_fp8_1(float f) {
  u32 u = __float_as_uint(f);
  u32 s = u >> 31;
  u32 mag = u & 0x7fffffffu;
  mag = mag + 0x7ffffu + ((mag >> 20) & 1u);          // RNE to 3 mant bits
  if (mag > 0x43e00000u) mag = 0x43e00000u;           // clamp to 448
  u32 e = mag >> 23;
  return (e <= 120u) ? 0u
                     : ((s << 7) | ((e - 120u) << 3) | ((mag >> 20) & 7u));
}

__device__ __forceinline__ u32 pack4_fp8(float a, float b, float c, float d) {
#if __has_builtin(__builtin_amdgcn_cvt_pk_fp8_f32)
  int v = 0;
  v = __builtin_amdgcn_cvt_pk_fp8_f32(a, b, v, false);  // bytes 0,1
  v = __builtin_amdgcn_cvt_pk_fp8_f32(c, d, v, true);   // bytes 2,3
  return (u32)v;
#else
  return enc_fp8_1(a) | (enc_fp8_1(b) << 8) | (enc_fp8_1(c) << 16) |
         (enc_fp8_1(d) << 24);
#endif
}

__device__ __forceinline__ float dec_fp8_1(u32 b) {
  u32 e = (b >> 3) & 15u;
  u32 f = ((b & 0x80u) << 24) | ((e + 120u) << 23) | ((b & 7u) << 20);
  return e ? __uint_as_float(f) : 0.0f;
}

__device__ __forceinline__ void acc4_fp8(float* a, u32 q) {
#if __has_builtin(__builtin_amdgcn_cvt_pk_f32_fp8)
  f32x2 p0 = __builtin_amdgcn_cvt_pk_f32_fp8((int)q, false);
  f32x2 p1 = __builtin_amdgcn_cvt_pk_f32_fp8((int)q, true);
  a[0] += p0.x; a[1] += p0.y; a[2] += p1.x; a[3] += p1.y;
#else
  a[0] += dec_fp8_1(q);       a[1] += dec_fp8_1(q >> 8);
  a[2] += dec_fp8_1(q >> 16); a[3] += dec_fp8_1(q >> 24);
#endif
}

// 16-byte global -> LDS async copy (wave-uniform LDS base + lane*16 layout)
#define GLD16(gp, lp)                                              \
  __builtin_amdgcn_global_load_lds(                                \
      (__attribute__((address_space(1))) u32*)(gp),                \
      (__attribute__((address_space(3))) u32*)(lp), 16, 0, 0)

// ---------------------------------------------------------------------------
// K1: LayerNorm (one-pass). Writes bf16 x into hcat[:, 2048:3072] AND fp8
// copy into dense xq[8192x1024] (aggregation gather input).
// ---------------------------------------------------------------------------
__global__ void ln_kernel(const float* __restrict__ hs,
                          const float* __restrict__ gamma,
                          const float* __restrict__ beta,
                          u16* __restrict__ hcat,
                          u32* __restrict__ xq) {
  const int row = blockIdx.x;
  const int tid = threadIdx.x;
  const float4 v = ((const float4*)(hs + (size_t)row * DDIM))[tid];

  __shared__ float r1[256], r2[256];
  r1[tid] = v.x + v.y + v.z + v.w;
  r2[tid] = v.x * v.x + v.y * v.y + v.z * v.z + v.w * v.w;
  __syncthreads();
  for (int st = 128; st > 0; st >>= 1) {
    if (tid < st) { r1[tid] += r1[tid + st]; r2[tid] += r2[tid + st]; }
    __syncthreads();
  }
  const float mean = r1[0] * (1.0f / DDIM);
  const float var  = r2[0] * (1.0f / DDIM) - mean * mean;
  const float rs   = rsqrtf(var + LN_EPS);

  const int base = tid * 4;
  const float4 g = *(const float4*)(gamma + base);
  const float4 b = *(const float4*)(beta + base);
  const float o0 = (v.x - mean) * rs * g.x + b.x;
  const float o1 = (v.y - mean) * rs * g.y + b.y;
  const float o2 = (v.z - mean) * rs * g.z + b.z;
  const float o3 = (v.w - mean) * rs * g.w + b.w;
  u16x4 o;
  o.x = f2bf(o0); o.y = f2bf(o1); o.z = f2bf(o2); o.w = f2bf(o3);
  *(u16x4*)(hcat + (size_t)row * KCAT + 2048 + base) = o;
  xq[row * 256 + tid] = pack4_fp8(o0, o1, o2, o3);
}

// ---------------------------------------------------------------------------
// K2: f32 [K,N] -> bf16 [N,K] transpose (stitches two sources along K).
// ---------------------------------------------------------------------------
__global__ void cvt_transpose(const float* __restrict__ srcA,
                              const float* __restrict__ srcB,
                              int splitK, int K, int N,
                              u16* __restrict__ dst) {
  __shared__ float tile[32][33];
  const int n0 = blockIdx.x * 32, k0 = blockIdx.y * 32;
  const int tx = threadIdx.x, ty = threadIdx.y;
  for (int i = ty; i < 32; i += 8) {
    const int k = k0 + i;
    const float v = (k < splitK) ? srcA[(size_t)k * N + n0 + tx]
                                 : srcB[(size_t)(k - splitK) * N + n0 + tx];
    tile[i][tx] = v;
  }
  __syncthreads();
  for (int i = ty; i < 32; i += 8) {
    dst[(size_t)(n0 + i) * K + k0 + tx] = f2bf(tile[tx][i]);
  }
}

// ---------------------------------------------------------------------------
// K3a: count edges per (rel,dst) bucket.
// ---------------------------------------------------------------------------
__global__ void count_kernel(const int* __restrict__ edge_index,
                             const int* __restrict__ edge_type,
                             int* __restrict__ cnt) {
  const int e = blockIdx.x * 256 + threadIdx.x;
  const int d = edge_index[E_NUM + e];
  const int r = edge_type[e];
  atomicAdd(&cnt[r * NNODE + d], 1);
}

// ---------------------------------------------------------------------------
// K3b: exclusive prefix sum over 16384 counts (single block, 1024 thr).
// ---------------------------------------------------------------------------
__global__ __launch_bounds__(1024) void scan_kernel(const int* __restrict__ cnt,
                                                    int* __restrict__ off,
                                                    int* __restrict__ cursor) {
  __shared__ int partial[1024];
  const int tid  = threadIdx.x;
  const int base = tid * 16;
  int local[16];
  int s = 0;
#pragma unroll
  for (int i = 0; i < 16; ++i) { local[i] = s; s += cnt[base + i]; }
  partial[tid] = s;
  __syncthreads();
  for (int st = 1; st < 1024; st <<= 1) {
    const int v = (tid >= st) ? partial[tid - st] : 0;
    __syncthreads();
    partial[tid] += v;
    __syncthreads();
  }
  const int pre = (tid == 0) ? 0 : partial[tid - 1];
#pragma unroll
  for (int i = 0; i < 16; ++i) {
    const int o = pre + local[i];
    off[base + i]    = o;
    cursor[base + i] = o;
  }
}

// ---------------------------------------------------------------------------
// K3c: scatter edge SOURCE ids into buckets (4B per edge, not row data).
// ---------------------------------------------------------------------------
__global__ void fill_kernel(const int* __restrict__ edge_index,
                            const int* __restrict__ edge_type,
                            int* __restrict__ cursor,
                            int* __restrict__ bucket_src) {
  const int e = blockIdx.x * 256 + threadIdx.x;
  const int s = edge_index[e];
  const int d = edge_index[E_NUM + e];
  const int r = edge_type[e];
  const int pos = atomicAdd(&cursor[r * NNODE + d], 1);
  bucket_src[pos] = s;
}

// ---------------------------------------------------------------------------
// K4: per-(rel,node) aggregation, fp8 gather. 4 edge-groups x 64 lanes; each
// lane covers 16 cols = one dwordx4 per edge (wave reads full 1KB fp8 row).
// Cross-group reduce via LDS; f32 accumulate; bf16 mean into hcat.
// ---------------------------------------------------------------------------
__global__ __launch_bounds__(256) void aggregate_kernel(
    const int* __restrict__ cnt, const int* __restrict__ off,
    const int* __restrict__ bucket_src, const u32* __restrict__ xq,
    u16* __restrict__ hcat) {
  const int b    = blockIdx.x;            // r*NNODE + node
  const int r    = b >> 13;
  const int node = b & (NNODE - 1);
  const int tid  = threadIdx.x;
  const int g    = tid >> 6;              // edge-group 0..3 (one wave each)
  const int c    = tid & 63;              // col chunk: cols c*16 .. c*16+15
  const int n     = cnt[b];
  const int start = off[b];

  __shared__ int   ids[256];
  __shared__ float red[3 * 1024];
  float a[16] = {};

  for (int c0 = 0; c0 < n; c0 += 256) {
    const int m = min(n - c0, 256);
    __syncthreads();
    if (tid < m) ids[tid] = bucket_src[start + c0 + tid];
    __syncthreads();
    int j = g;
    for (; j + 4 < m; j += 8) {           // unroll 2 (group stride 4)
      const int s0 = ids[j], s1 = ids[j + 4];
      const uint4 x0 = *(const uint4*)(xq + s0 * 256 + c * 4);
      const uint4 x1 = *(const uint4*)(xq + s1 * 256 + c * 4);
      acc4_fp8(a + 0,  x0.x); acc4_fp8(a + 4,  x0.y);
      acc4_fp8(a + 8,  x0.z); acc4_fp8(a + 12, x0.w);
      acc4_fp8(a + 0,  x1.x); acc4_fp8(a + 4,  x1.y);
      acc4_fp8(a + 8,  x1.z); acc4_fp8(a + 12, x1.w);
    }
    for (; j < m; j += 4) {               // remainder
      const int s0 = ids[j];
      const uint4 x0 = *(const uint4*)(xq + s0 * 256 + c * 4);
      acc4_fp8(a + 0,  x0.x); acc4_fp8(a + 4,  x0.y);
      acc4_fp8(a + 8,  x0.z); acc4_fp8(a + 12, x0.w);
    }
  }

  if (g != 0) {
    float* d = red + (g - 1) * 1024 + c * 16;
#pragma unroll
    for (int i = 0; i < 4; ++i)
      *(float4*)(d + i * 4) = make_float4(a[i*4+0], a[i*4+1], a[i*4+2], a[i*4+3]);
  }
  __syncthreads();
  if (g == 0) {
#pragma unroll
    for (int k = 0; k < 3; ++k) {
      const float* d = red + k * 1024 + c * 16;
#pragma unroll
      for (int i = 0; i < 16; ++i) a[i] += d[i];
    }
    const float inv = 1.0f / fmaxf((float)n, 1.0f);
    uint4 o0, o1;
    o0.x = (u32)f2bf(a[0] * inv)  | ((u32)f2bf(a[1] * inv)  << 16);
    o0.y = (u32)f2bf(a[2] * inv)  | ((u32)f2bf(a[3] * inv)  << 16);
    o0.z = (u32)f2bf(a[4] * inv)  | ((u32)f2bf(a[5] * inv)  << 16);
    o0.w = (u32)f2bf(a[6] * inv)  | ((u32)f2bf(a[7] * inv)  << 16);
    o1.x = (u32)f2bf(a[8] * inv)  | ((u32)f2bf(a[9] * inv)  << 16);
    o1.y = (u32)f2bf(a[10] * inv) | ((u32)f2bf(a[11] * inv) << 16);
    o1.z = (u32)f2bf(a[12] * inv) | ((u32)f2bf(a[13] * inv) << 16);
    o1.w = (u32)f2bf(a[14] * inv) | ((u32)f2bf(a[15] * inv) << 16);
    u16* dp = hcat + (size_t)node * KCAT + (size_t)r * DDIM + c * 16;
    *(uint4*)(dp)     = o0;
    *(uint4*)(dp + 8) = o1;
  }
}

// ---------------------------------------------------------------------------
// GEMM1: out1[8192x4096] = bf16(relu(hcat[8192x3072] @ WcatT^T + bias))
// 128x128 tile, BK=64, XOR-swizzled LDS (R3: conflicts 0, 936 TF plateau).
// ---------------------------------------------------------------------------
__global__ __launch_bounds__(256) void gemm1_kernel(
    const u16* __restrict__ A, const u16* __restrict__ Bt,
    const float* __restrict__ bias, u16* __restrict__ obf) {
  const int K = KCAT, N = FDIM;
  __shared__ __align__(16) u16 sA[128 * 64];
  __shared__ __align__(16) u16 sB[128 * 64];
  const int tid  = threadIdx.x;
  const int lane = tid & 63;
  const int wave = tid >> 6;
  const int bm = blockIdx.x * 128;
  const int bn = blockIdx.y * 128;
  const int wm = (wave >> 1) * 64;
  const int wn = (wave & 1) * 64;
  const int lr   = lane & 15;
  const int quad = lane >> 4;

  f32x4 acc[4][4] = {};

  const u16* gA[4]; const u16* gB[4]; u16* lA[4]; u16* lB[4];
#pragma unroll
  for (int i = 0; i < 4; ++i) {
    const int s   = tid + 256 * i;
    const int row = s >> 3;
    const int seg = (s & 7) ^ (row & 7);
    gA[i] = A  + (size_t)(bm + row) * K + seg * 8;
    gB[i] = Bt + (size_t)(bn + row) * K + seg * 8;
    lA[i] = sA + s * 8;
    lB[i] = sB + s * 8;
  }

  int ai[4][2], bi[4][2];
#pragma unroll
  for (int mi = 0; mi < 4; ++mi) {
#pragma unroll
    for (int h = 0; h < 2; ++h) {
      const int ra = wm + mi * 16 + lr;
      ai[mi][h] = ra * 8 + ((h * 4 + quad) ^ (ra & 7));
      const int rb = wn + mi * 16 + lr;
      bi[mi][h] = rb * 8 + ((h * 4 + quad) ^ (rb & 7));
    }
  }

  for (int k0 = 0; k0 < K; k0 += 64) {
#pragma unroll
    for (int i = 0; i < 4; ++i) {
      GLD16(gA[i] + k0, lA[i]);
      GLD16(gB[i] + k0, lB[i]);
    }
    __syncthreads();

    const bf16x8* pA = (const bf16x8*)sA;
    const bf16x8* pB = (const bf16x8*)sB;
#pragma unroll
    for (int h = 0; h < 2; ++h) {
      bf16x8 av[4], bv[4];
#pragma unroll
      for (int mi = 0; mi < 4; ++mi) av[mi] = pA[ai[mi][h]];
#pragma unroll
      for (int ni = 0; ni < 4; ++ni) bv[ni] = pB[bi[ni][h]];
#pragma unroll
      for (int mi = 0; mi < 4; ++mi)
#pragma unroll
        for (int ni = 0; ni < 4; ++ni)
          acc[mi][ni] = __builtin_amdgcn_mfma_f32_16x16x32_bf16(
              av[mi], bv[ni], acc[mi][ni], 0, 0, 0);
    }
    __syncthreads();
  }

#pragma unroll
  for (int mi = 0; mi < 4; ++mi) {
#pragma unroll
    for (int ni = 0; ni < 4; ++ni) {
      const int col  = bn + wn + ni * 16 + lr;
      const int row0 = bm + wm + mi * 16 + quad * 4;
      const float bb = bias[col];
#pragma unroll
      for (int r = 0; r < 4; ++r) {
        float v = acc[mi][ni][r] + bb;
        v = fmaxf(v, 0.0f);
        obf[(size_t)(row0 + r) * N + col] = f2bf(v);
      }
    }
  }
}

// ---------------------------------------------------------------------------
// GEMM2: out[8192x1024] = resid + out1[8192x4096] @ woT^T
// R6: 64x128 tile (grid 128x8 = 1024 blocks, 4/CU — was 512/2 per CU and
// barrier-drain exposed). BK=64, same XOR swizzle. 24KB LDS. 2x4 acc/wave.
// ---------------------------------------------------------------------------
__global__ __launch_bounds__(256) void gemm2_kernel(
    const u16* __restrict__ A, const u16* __restrict__ Bt,
    const float* __restrict__ resid, float* __restrict__ out) {
  const int K = FDIM, N = DDIM;
  __shared__ __align__(16) u16 sA[64 * 64];    //  8 KB
  __shared__ __align__(16) u16 sB[128 * 64];   // 16 KB
  const int tid  = threadIdx.x;
  const int lane = tid & 63;
  const int wave = tid >> 6;
  const int bm = blockIdx.x * 64;
  const int bn = blockIdx.y * 128;
  const int wm = (wave >> 1) * 32;
  const int wn = (wave & 1) * 64;
  const int lr   = lane & 15;
  const int quad = lane >> 4;

  f32x4 acc[2][4] = {};

  // staging: A 512 slots (2/thread), B 1024 slots (4/thread)
  const u16* gA[2]; u16* lA[2];
#pragma unroll
  for (int i = 0; i < 2; ++i) {
    const int s   = tid + 256 * i;
    const int row = s >> 3;
    const int seg = (s & 7) ^ (row & 7);
    gA[i] = A + (size_t)(bm + row) * K + seg * 8;
    lA[i] = sA + s * 8;
  }
  const u16* gB[4]; u16* lB[4];
#pragma unroll
  for (int i = 0; i < 4; ++i) {
    const int s   = tid + 256 * i;
    const int row = s >> 3;
    const int seg = (s & 7) ^ (row & 7);
    gB[i] = Bt + (size_t)(bn + row) * K + seg * 8;
    lB[i] = sB + s * 8;
  }

  int ai[2][2], bi[4][2];
#pragma unroll
  for (int h = 0; h < 2; ++h) {
#pragma unroll
    for (int mi = 0; mi < 2; ++mi) {
      const int ra = wm + mi * 16 + lr;
      ai[mi][h] = ra * 8 + ((h * 4 + quad) ^ (ra & 7));
    }
#pragma unroll
    for (int ni = 0; ni < 4; ++ni) {
      const int rb = wn + ni * 16 + lr;
      bi[ni][h] = rb * 8 + ((h * 4 + quad) ^ (rb & 7));
    }
  }

  for (int k0 = 0; k0 < K; k0 += 64) {
#pragma unroll
    for (int i = 0; i < 2; ++i) GLD16(gA[i] + k0, lA[i]);
#pragma unroll
    for (int i = 0; i < 4; ++i) GLD16(gB[i] + k0, lB[i]);
    __syncthreads();

    const bf16x8* pA = (const bf16x8*)sA;
    const bf16x8* pB = (const bf16x8*)sB;
#pragma unroll
    for (int h = 0; h < 2; ++h) {
      bf16x8 av[2], bv[4];
#pragma unroll
      for (int mi = 0; mi < 2; ++mi) av[mi] = pA[ai[mi][h]];
#pragma unroll
      for (int ni = 0; ni < 4; ++ni) bv[ni] = pB[bi[ni][h]];
#pragma unroll
      for (int mi = 0; mi < 2; ++mi)
#pragma unroll
        for (int ni = 0; ni < 4; ++ni)
          acc[mi][ni] = __builtin_amdgcn_mfma_f32_16x16x32_bf16(
              av[mi], bv[ni], acc[mi][ni], 0, 0, 0);
    }
    __syncthreads();
  }

#pragma unroll
  for (int mi = 0; mi < 2; ++mi) {
#pragma unroll
    for (int ni = 0; ni < 4; ++ni) {
      const int col  = bn + wn + ni * 16 + lr;
      const int row0 = bm + wm + mi * 16 + quad * 4;
#pragma unroll
      for (int r = 0; r < 4; ++r) {
        const size_t idx = (size_t)(row0 + r) * N + col;
        out[idx] = resid[idx] + acc[mi][ni][r];
      }
    }
  }
}

// ---------------------------------------------------------------------------
// Workspace layout (bytes):
//   hcat       [8192 x 3072] bf16              @ 0          (50331648)
//   WcatT      [4096 x 3072] bf16              @ 50331648   (25165824)
//   woT        [1024 x 4096] bf16              @ 75497472   ( 8388608)
//   out1       [8192 x 4096] bf16              @ 83886080   (67108864)
//     bucket_src [262144] i32 (aliases out1)   @ 83886080   ( 1048576)
//     cnt        [16384] i32                   @ 84934656   (   65536)
//     off        [16384] i32                   @ 85000192   (   65536)
//     cursor     [16384] i32                   @ 85065728   (   65536)
//     xq         [8192 x 1024] fp8             @ 85131264   ( 8388608)
//   (all aliased scratch consumed before GEMM1 writes out1)
// total: 150994944 bytes (144 MB)
// ---------------------------------------------------------------------------
extern "C" void kernel_launch(void* const* d_in, const int* in_sizes, int n_in,
                              void* d_out, int out_size, void* d_ws, size_t ws_size,
                              hipStream_t stream) {
  const float* hs     = (const float*)d_in[0];
  const float* weight = (const float*)d_in[1];   // [2,1024,4096]
  const float* root   = (const float*)d_in[2];   // [1024,4096]
  const float* bias   = (const float*)d_in[3];   // [4096]
  const float* wo     = (const float*)d_in[4];   // [4096,1024]
  const float* gamma  = (const float*)d_in[5];
  const float* beta   = (const float*)d_in[6];
  const int* edge_index = (const int*)d_in[7];   // [2,E]
  const int* edge_type  = (const int*)d_in[8];   // [E]
  float* out = (float*)d_out;

  char* ws = (char*)d_ws;
  u16*   hcat       = (u16*)(ws + 0);
  u16*   WcatT      = (u16*)(ws + 50331648);
  u16*   woT        = (u16*)(ws + 75497472);
  u16*   out1       = (u16*)(ws + 83886080);
  int*   bucket_src = (int*)(ws + 83886080);     // aliases out1 (consumed pre-GEMM1)
  int*   cnt        = (int*)(ws + 84934656);
  int*   off        = (int*)(ws + 85000192);
  int*   cursor     = (int*)(ws + 85065728);
  u32*   xq         = (u32*)(ws + 85131264);     // fp8 x, dense [8192][1024]

  (void)hipMemsetAsync(cnt, 0, 65536, stream);

  ln_kernel<<<NNODE, 256, 0, stream>>>(hs, gamma, beta, hcat, xq);

  cvt_transpose<<<dim3(FDIM / 32, KCAT / 32), dim3(32, 8), 0, stream>>>(
      weight, root, 2048, KCAT, FDIM, WcatT);
  cvt_transpose<<<dim3(DDIM / 32, FDIM / 32), dim3(32, 8), 0, stream>>>(
      wo, wo, FDIM, FDIM, DDIM, woT);

  count_kernel<<<E_NUM / 256, 256, 0, stream>>>(edge_index, edge_type, cnt);
  scan_kernel<<<1, 1024, 0, stream>>>(cnt, off, cursor);
  fill_kernel<<<E_NUM / 256, 256, 0, stream>>>(edge_index, edge_type, cursor, bucket_src);
  aggregate_kernel<<<NBKT, 256, 0, stream>>>(cnt, off, bucket_src, xq, hcat);

  // out1 = relu([h0|h1|x] @ [W0;W1;root] + bias)   [8192 x 4096] bf16
  gemm1_kernel<<<dim3(8192 / 128, FDIM / 128), 256, 0, stream>>>(
      hcat, WcatT, bias, out1);

  // out = hs + out1 @ wo                            [8192 x 1024] f32
  gemm2_kernel<<<dim3(8192 / 64, DDIM / 128), 256, 0, stream>>>(
      out1, woT, hs, out);
}